// Round 4
// baseline (40.610 us; speedup 1.0000x reference)
//
#include <hip/hip_runtime.h>
#include <hip/hip_bf16.h>
#include <stdint.h>

#define N_NODES 4096
#define BATCH 2

typedef __attribute__((ext_vector_type(8))) short short8v;
typedef __attribute__((ext_vector_type(4))) unsigned short ushort4v;
typedef __attribute__((ext_vector_type(4))) float f32x4;

static __device__ inline unsigned short f2bf_rn(float x) {
    unsigned u = __float_as_uint(x);
    unsigned r = (u + 0x7FFFu + ((u >> 16) & 1u)) >> 16;
    return (unsigned short)r;
}
static __device__ inline float bf2f(unsigned short b) {
    return __uint_as_float(((unsigned)b) << 16);
}
static __device__ inline float rl(float v, int k) {   // wave-uniform broadcast
    return __uint_as_float(__builtin_amdgcn_readlane(__float_as_uint(v), k));
}

// ---------------------------------------------------------------------------
// K1 fat kernel.
//  blocks [0,1024): fused normalize + adjacency 128x128 MFMA tile -> bitmask
//  blocks [1024,1280): feat1 = proj + mm1 + scores1 (8 rows/wave)
// ---------------------------------------------------------------------------
__global__ __launch_bounds__(256) void k1_kernel(
        const float* __restrict__ emb, unsigned long long* __restrict__ mask,
        const float* __restrict__ x, const float* __restrict__ Wp,
        const float* __restrict__ bp, const float* __restrict__ W1,
        const float* __restrict__ a1s, const float* __restrict__ a1d,
        float* __restrict__ h1out, float* __restrict__ ssrc, float* __restrict__ sdst) {
    __shared__ unsigned short Ah[128 * 64];
    __shared__ unsigned short Al[128 * 64];
    __shared__ unsigned short Bh[128 * 64];
    __shared__ unsigned short Bl[128 * 64];
    int t = threadIdx.x;

    if (blockIdx.x < 1024) {
        // ================= adjacency =================
        int bi = blockIdx.x >> 5, bj = blockIdx.x & 31;
        int i0 = bi * 128, j0 = bj * 128;
        int w = t >> 6, l = t & 63;

        // ---- stage: normalize rows in-register, split bf16, swizzled write ----
        int l16 = t & 15;
        int s8 = l16 >> 1, hf = l16 & 1;
#pragma unroll
        for (int it = 0; it < 8; ++it) {
            int r = it * 16 + (t >> 4);
            float4 av = *(const float4*)&emb[(size_t)(i0 + r) * 64 + l16 * 4];
            float4 bv = *(const float4*)&emb[(size_t)(j0 + r) * 64 + l16 * 4];
            float sa = av.x * av.x + av.y * av.y + av.z * av.z + av.w * av.w;
            float sb = bv.x * bv.x + bv.y * bv.y + bv.z * bv.z + bv.w * bv.w;
#pragma unroll
            for (int m = 8; m >= 1; m >>= 1) {
                sa += __shfl_xor(sa, m);
                sb += __shfl_xor(sb, m);
            }
            float ia = 1.f / sqrtf(sa), ib = 1.f / sqrtf(sb);
            float a0 = av.x * ia, a1 = av.y * ia, a2 = av.z * ia, a3 = av.w * ia;
            float b0 = bv.x * ib, b1 = bv.y * ib, b2 = bv.z * ib, b3 = bv.w * ib;
            ushort4v ah = {f2bf_rn(a0), f2bf_rn(a1), f2bf_rn(a2), f2bf_rn(a3)};
            ushort4v bh = {f2bf_rn(b0), f2bf_rn(b1), f2bf_rn(b2), f2bf_rn(b3)};
            ushort4v al = {f2bf_rn(a0 - bf2f(ah.x)), f2bf_rn(a1 - bf2f(ah.y)),
                           f2bf_rn(a2 - bf2f(ah.z)), f2bf_rn(a3 - bf2f(ah.w))};
            ushort4v bl = {f2bf_rn(b0 - bf2f(bh.x)), f2bf_rn(b1 - bf2f(bh.y)),
                           f2bf_rn(b2 - bf2f(bh.z)), f2bf_rn(b3 - bf2f(bh.w))};
            int si = r * 64 + ((s8 ^ (r & 7)) << 3) + hf * 4;
            *(ushort4v*)&Ah[si] = ah;
            *(ushort4v*)&Al[si] = al;
            *(ushort4v*)&Bh[si] = bh;
            *(ushort4v*)&Bl[si] = bl;
        }
        __syncthreads();

        // ---- fragments + MFMA (layout identical to verified R2 kernel) ----
        int fr = l & 15;
        int s0 = l >> 4;
        int r7 = l & 7;
        short8v aH[2][2], aL[2][2];
#pragma unroll
        for (int rt = 0; rt < 2; ++rt) {
            int base = (w * 32 + rt * 16 + fr) * 64;
            aH[rt][0] = *(const short8v*)&Ah[base + ((s0 ^ r7) << 3)];
            aH[rt][1] = *(const short8v*)&Ah[base + (((s0 + 4) ^ r7) << 3)];
            aL[rt][0] = *(const short8v*)&Al[base + ((s0 ^ r7) << 3)];
            aL[rt][1] = *(const short8v*)&Al[base + (((s0 + 4) ^ r7) << 3)];
        }

        f32x4 acc[2][8];
#pragma unroll
        for (int rt = 0; rt < 2; ++rt)
#pragma unroll
            for (int js = 0; js < 8; ++js) acc[rt][js] = (f32x4){0.f, 0.f, 0.f, 0.f};

#pragma unroll
        for (int js = 0; js < 8; ++js) {
            int bbase = (js * 16 + fr) * 64;
            short8v bH0 = *(const short8v*)&Bh[bbase + ((s0 ^ r7) << 3)];
            short8v bH1 = *(const short8v*)&Bh[bbase + (((s0 + 4) ^ r7) << 3)];
            short8v bL0 = *(const short8v*)&Bl[bbase + ((s0 ^ r7) << 3)];
            short8v bL1 = *(const short8v*)&Bl[bbase + (((s0 + 4) ^ r7) << 3)];
#pragma unroll
            for (int rt = 0; rt < 2; ++rt) {
                f32x4 a = acc[rt][js];
                a = __builtin_amdgcn_mfma_f32_16x16x32_bf16(aH[rt][0], bH0, a, 0, 0, 0);
                a = __builtin_amdgcn_mfma_f32_16x16x32_bf16(aH[rt][1], bH1, a, 0, 0, 0);
                a = __builtin_amdgcn_mfma_f32_16x16x32_bf16(aH[rt][0], bL0, a, 0, 0, 0);
                a = __builtin_amdgcn_mfma_f32_16x16x32_bf16(aH[rt][1], bL1, a, 0, 0, 0);
                a = __builtin_amdgcn_mfma_f32_16x16x32_bf16(aL[rt][0], bH0, a, 0, 0, 0);
                a = __builtin_amdgcn_mfma_f32_16x16x32_bf16(aL[rt][1], bH1, a, 0, 0, 0);
                acc[rt][js] = a;
            }
        }

        // ---- pack to bitmask. C/D layout: col=lane&15, row=(lane>>4)*4+reg ----
        int shift = ((l & 15) >> 2) * 16;
        int r = l & 3;
#pragma unroll
        for (int rt = 0; rt < 2; ++rt) {
#pragma unroll
            for (int ws_ = 0; ws_ < 2; ++ws_) {
                unsigned long long w64 = 0;
#pragma unroll
                for (int js2 = 0; js2 < 4; ++js2) {
                    f32x4 a = acc[rt][ws_ * 4 + js2];
                    unsigned long long c0 = __ballot(a[0] > 0.5f);
                    unsigned long long c1 = __ballot(a[1] > 0.5f);
                    unsigned long long c2 = __ballot(a[2] > 0.5f);
                    unsigned long long c3 = __ballot(a[3] > 0.5f);
                    unsigned long long sel = r == 0 ? c0 : r == 1 ? c1 : r == 2 ? c2 : c3;
                    w64 |= ((sel >> shift) & 0xFFFFULL) << (js2 * 16);
                }
                if (l < 16)
                    mask[(size_t)(i0 + w * 32 + rt * 16 + l) * 64 + bj * 2 + ws_] = w64;
            }
        }
    } else {
        // ================= feat1: proj + mm1 + scores1 =================
        int b = blockIdx.x - 1024;
        int w = t >> 6, l = t & 63;
        int row0 = b * 32 + w * 8;

        float xv[8];
#pragma unroll
        for (int r = 0; r < 8; ++r) xv[r] = x[(size_t)(row0 + r) * 16 + (l & 15)];

        float h0[8];
        float bpv = bp[l];
#pragma unroll
        for (int r = 0; r < 8; ++r) h0[r] = bpv;
#pragma unroll
        for (int k = 0; k < 16; ++k) {
            float wk = Wp[k * 64 + l];
#pragma unroll
            for (int r = 0; r < 8; ++r) h0[r] += rl(xv[r], k) * wk;
        }

        float h1[8] = {0.f, 0.f, 0.f, 0.f, 0.f, 0.f, 0.f, 0.f};
#pragma unroll
        for (int k = 0; k < 64; ++k) {
            float wk = W1[k * 64 + l];
#pragma unroll
            for (int r = 0; r < 8; ++r) h1[r] += rl(h0[r], k) * wk;
        }

        float as_ = a1s[l], ad_ = a1d[l];
#pragma unroll
        for (int r = 0; r < 8; ++r) {
            h1out[(size_t)(row0 + r) * 64 + l] = h1[r];
            float ps = h1[r] * as_, pd = h1[r] * ad_;
#pragma unroll
            for (int m = 8; m >= 1; m >>= 1) {
                ps += __shfl_xor(ps, m);
                pd += __shfl_xor(pd, m);
            }
            if ((l & 15) == 0) {
                ssrc[(size_t)(row0 + r) * 4 + (l >> 4)] = ps;
                sdst[(size_t)(row0 + r) * 4 + (l >> 4)] = pd;
            }
        }
    }
}

// ---------------------------------------------------------------------------
// K2: GAT-1 aggregation (+bias+ReLU) + mm2 + scores2. 4 rows/block, wave/row.
// ---------------------------------------------------------------------------
__global__ __launch_bounds__(256) void agg1_fused_kernel(
        const float* __restrict__ h1, const float* __restrict__ ssrc,
        const float* __restrict__ sdst, const unsigned long long* __restrict__ mask,
        const float* __restrict__ b1, const float* __restrict__ W2,
        const float* __restrict__ a2s, const float* __restrict__ a2d,
        float* __restrict__ h2out, float* __restrict__ s2s, float* __restrict__ s2d) {
    int row = blockIdx.x * 4 + (threadIdx.x >> 6);
    int i = row & (N_NODES - 1);
    int bN = row - i;
    int t = threadIdx.x & 63;
    int hh = t >> 4;

    float sd = sdst[(size_t)row * 4 + hh];
    unsigned long long myword = mask[(size_t)i * 64 + t];

    float m = -1e30f, denom = 0.f, acc = 0.f;
    unsigned long long nz = __ballot(myword != 0ULL);
    while (nz) {
        int lw = __ffsll(nz) - 1;
        nz &= nz - 1;
        unsigned long long wbits = __shfl(myword, lw);
        while (wbits) {
            int bpos = __ffsll(wbits) - 1;
            wbits &= wbits - 1;
            int j = (lw << 6) + bpos;
            float e = sd + ssrc[(size_t)(bN + j) * 4 + hh];
            e = e > 0.f ? e : 0.2f * e;
            float mn = fmaxf(m, e);
            float cf = __expf(m - mn);
            float wg = __expf(e - mn);
            float hv = h1[(size_t)(bN + j) * 64 + t];
            denom = denom * cf + wg;
            acc = acc * cf + wg * hv;
            m = mn;
        }
    }
    float o = fmaxf(acc / denom + b1[t], 0.f);   // out1 row, lane t = feature t

    // mm2: h2[t'] = sum_k o_k * W2[k*32+t']  (lanes 32..63 duplicate 0..31)
    int l2 = t & 31;
    float acc2 = 0.f;
#pragma unroll
    for (int k = 0; k < 64; ++k) acc2 += rl(o, k) * W2[k * 32 + l2];

    float ps = acc2 * a2s[l2], pd = acc2 * a2d[l2];
#pragma unroll
    for (int mm = 4; mm >= 1; mm >>= 1) {
        ps += __shfl_xor(ps, mm);
        pd += __shfl_xor(pd, mm);
    }
    if (t < 32) {
        h2out[(size_t)row * 32 + t] = acc2;
        if ((t & 7) == 0) {
            s2s[(size_t)row * 4 + (t >> 3)] = ps;
            s2d[(size_t)row * 4 + (t >> 3)] = pd;
        }
    }
}

// ---------------------------------------------------------------------------
// K3: GAT-2 aggregation -> d_out. 4 rows/block, wave/row.
// ---------------------------------------------------------------------------
__global__ __launch_bounds__(256) void agg2_kernel(
        const float* __restrict__ hfeat, const float* __restrict__ ssrc,
        const float* __restrict__ sdst, const unsigned long long* __restrict__ mask,
        const float* __restrict__ bias, float* __restrict__ out) {
    int row = blockIdx.x * 4 + (threadIdx.x >> 6);
    int i = row & (N_NODES - 1);
    int bN = row - i;
    int t = threadIdx.x & 63;
    int tt = t & 31;
    int hh = tt >> 3;

    float sd = sdst[(size_t)row * 4 + hh];
    unsigned long long myword = mask[(size_t)i * 64 + t];

    float m = -1e30f, denom = 0.f, acc = 0.f;
    unsigned long long nz = __ballot(myword != 0ULL);
    while (nz) {
        int lw = __ffsll(nz) - 1;
        nz &= nz - 1;
        unsigned long long wbits = __shfl(myword, lw);
        while (wbits) {
            int bpos = __ffsll(wbits) - 1;
            wbits &= wbits - 1;
            int j = (lw << 6) + bpos;
            float e = sd + ssrc[(size_t)(bN + j) * 4 + hh];
            e = e > 0.f ? e : 0.2f * e;
            float mn = fmaxf(m, e);
            float cf = __expf(m - mn);
            float wg = __expf(e - mn);
            float hv = hfeat[(size_t)(bN + j) * 32 + tt];
            denom = denom * cf + wg;
            acc = acc * cf + wg * hv;
            m = mn;
        }
    }
    float o = acc / denom + bias[tt];
    if (t < 32) out[(size_t)row * 32 + tt] = o;
}

// ---------------------------------------------------------------------------
extern "C" void kernel_launch(void* const* d_in, const int* in_sizes, int n_in,
                              void* d_out, int out_size, void* d_ws, size_t ws_size,
                              hipStream_t stream) {
    const float* x   = (const float*)d_in[0];
    const float* emb = (const float*)d_in[1];
    const float* Wp  = (const float*)d_in[2];
    const float* bp  = (const float*)d_in[3];
    const float* W1  = (const float*)d_in[4];
    const float* a1s = (const float*)d_in[5];
    const float* a1d = (const float*)d_in[6];
    const float* b1  = (const float*)d_in[7];
    const float* W2  = (const float*)d_in[8];
    const float* a2s = (const float*)d_in[9];
    const float* a2d = (const float*)d_in[10];
    const float* b2  = (const float*)d_in[11];

    const int ROWS = BATCH * N_NODES;  // 8192

    char* w = (char*)d_ws;
    unsigned long long* mask = (unsigned long long*)w; w += (size_t)N_NODES * 64 * 8;
    float* h1  = (float*)w;                      w += (size_t)ROWS * 64 * 4;
    float* s1s = (float*)w;                      w += (size_t)ROWS * 4 * 4;
    float* s1d = (float*)w;                      w += (size_t)ROWS * 4 * 4;
    float* h2  = (float*)w;                      w += (size_t)ROWS * 32 * 4;
    float* s2s = (float*)w;                      w += (size_t)ROWS * 4 * 4;
    float* s2d = (float*)w;                      w += (size_t)ROWS * 4 * 4;

    k1_kernel<<<dim3(1024 + 256), dim3(256), 0, stream>>>(
        emb, mask, x, Wp, bp, W1, a1s, a1d, h1, s1s, s1d);
    agg1_fused_kernel<<<dim3(ROWS / 4), dim3(256), 0, stream>>>(
        h1, s1s, s1d, mask, b1, W2, a2s, a2d, h2, s2s, s2d);
    agg2_kernel<<<dim3(ROWS / 4), dim3(256), 0, stream>>>(
        h2, s2s, s2d, mask, b2, (float*)d_out);
}

// Round 5
// 37.433 us; speedup vs baseline: 1.0849x; 1.0849x over previous
//
#include <hip/hip_runtime.h>
#include <hip/hip_bf16.h>
#include <stdint.h>

#define N_NODES 4096
#define BATCH 2

typedef __attribute__((ext_vector_type(8))) short short8v;
typedef __attribute__((ext_vector_type(4))) unsigned short ushort4v;
typedef __attribute__((ext_vector_type(4))) float f32x4;

#define GLL16(gsrc, ldst) \
    __builtin_amdgcn_global_load_lds((const __attribute__((address_space(1))) void*)(gsrc), \
                                     (__attribute__((address_space(3))) void*)(ldst), 16, 0, 0)

static __device__ inline unsigned short f2bf_rn(float x) {
    unsigned u = __float_as_uint(x);
    unsigned r = (u + 0x7FFFu + ((u >> 16) & 1u)) >> 16;
    return (unsigned short)r;
}
static __device__ inline float bf2f(unsigned short b) {
    return __uint_as_float(((unsigned)b) << 16);
}
static __device__ inline float rl(float v, int k) {   // wave-uniform broadcast
    return __uint_as_float(__builtin_amdgcn_readlane(__float_as_uint(v), k));
}

// ---------------------------------------------------------------------------
// K1 fat kernel (no LDS):
//  blocks [0,256):   normalize 16 rows/block -> split-bf16 ne_hi/ne_lo (ONCE)
//  blocks [256,512): feat1 = proj + mm1 + scores1 (8 rows/wave)
// ---------------------------------------------------------------------------
__global__ __launch_bounds__(256) void k1_kernel(
        const float* __restrict__ emb,
        unsigned short* __restrict__ ne_hi, unsigned short* __restrict__ ne_lo,
        const float* __restrict__ x, const float* __restrict__ Wp,
        const float* __restrict__ bp, const float* __restrict__ W1,
        const float* __restrict__ a1s, const float* __restrict__ a1d,
        float* __restrict__ h1out, float* __restrict__ ssrc, float* __restrict__ sdst) {
    int t = threadIdx.x;
    if (blockIdx.x < 256) {
        // ---------------- norm: 16 rows per block, one row per 16 lanes ----
        int row = blockIdx.x * 16 + (t >> 4);
        int l16 = t & 15;
        float4 v = *(const float4*)&emb[(size_t)row * 64 + l16 * 4];
        float s = v.x * v.x + v.y * v.y + v.z * v.z + v.w * v.w;
#pragma unroll
        for (int m = 8; m >= 1; m >>= 1) s += __shfl_xor(s, m);
        float inv = 1.f / sqrtf(s);
        float n0 = v.x * inv, n1 = v.y * inv, n2 = v.z * inv, n3 = v.w * inv;
        ushort4v h = {f2bf_rn(n0), f2bf_rn(n1), f2bf_rn(n2), f2bf_rn(n3)};
        ushort4v lo = {f2bf_rn(n0 - bf2f(h.x)), f2bf_rn(n1 - bf2f(h.y)),
                       f2bf_rn(n2 - bf2f(h.z)), f2bf_rn(n3 - bf2f(h.w))};
        *(ushort4v*)&ne_hi[(size_t)row * 64 + l16 * 4] = h;
        *(ushort4v*)&ne_lo[(size_t)row * 64 + l16 * 4] = lo;
    } else {
        // ---------------- feat1: proj + mm1 + scores1 ----------------------
        int b = blockIdx.x - 256;
        int w = t >> 6, l = t & 63;
        int row0 = b * 32 + w * 8;

        float xv[8];
#pragma unroll
        for (int r = 0; r < 8; ++r) xv[r] = x[(size_t)(row0 + r) * 16 + (l & 15)];

        float h0[8];
        float bpv = bp[l];
#pragma unroll
        for (int r = 0; r < 8; ++r) h0[r] = bpv;
#pragma unroll
        for (int k = 0; k < 16; ++k) {
            float wk = Wp[k * 64 + l];
#pragma unroll
            for (int r = 0; r < 8; ++r) h0[r] += rl(xv[r], k) * wk;
        }

        float h1[8] = {0.f, 0.f, 0.f, 0.f, 0.f, 0.f, 0.f, 0.f};
#pragma unroll
        for (int k = 0; k < 64; ++k) {
            float wk = W1[k * 64 + l];
#pragma unroll
            for (int r = 0; r < 8; ++r) h1[r] += rl(h0[r], k) * wk;
        }

        float as_ = a1s[l], ad_ = a1d[l];
#pragma unroll
        for (int r = 0; r < 8; ++r) {
            h1out[(size_t)(row0 + r) * 64 + l] = h1[r];
            float ps = h1[r] * as_, pd = h1[r] * ad_;
#pragma unroll
            for (int m = 8; m >= 1; m >>= 1) {
                ps += __shfl_xor(ps, m);
                pd += __shfl_xor(pd, m);
            }
            if ((l & 15) == 0) {
                ssrc[(size_t)(row0 + r) * 4 + (l >> 4)] = ps;
                sdst[(size_t)(row0 + r) * 4 + (l >> 4)] = pd;
            }
        }
    }
}

// ---------------------------------------------------------------------------
// K2: adjacency bitmask, 128x128 tile/block, LDS-staged split-bf16 MFMA GEMM.
//    (R2-verified version: global_load_lds staging, pre-swizzled source.)
// ---------------------------------------------------------------------------
__global__ __launch_bounds__(256) void adj_mfma_kernel(
        const unsigned short* __restrict__ hi, const unsigned short* __restrict__ lo,
        unsigned long long* __restrict__ mask) {
    __shared__ unsigned short Ah[128 * 64];
    __shared__ unsigned short Al[128 * 64];
    __shared__ unsigned short Bh[128 * 64];
    __shared__ unsigned short Bl[128 * 64];
    int t = threadIdx.x;
    int w = t >> 6, l = t & 63;
    int i0 = blockIdx.y * 128, j0 = blockIdx.x * 128;

    // ---- stage: wave w stages local rows [w*32, w*32+32) of each buffer ----
    int cr = l >> 3;                 // row within 8-row chunk
    int slot = (l & 7) ^ cr;         // pre-swizzled source 16B-slot
#pragma unroll
    for (int q = 0; q < 4; ++q) {
        int lr = w * 32 + q * 8;     // local chunk base row
        size_t ga = (size_t)(i0 + lr + cr) * 64 + slot * 8;
        size_t gb = (size_t)(j0 + lr + cr) * 64 + slot * 8;
        GLL16(hi + ga, &Ah[lr * 64]);
        GLL16(lo + ga, &Al[lr * 64]);
        GLL16(hi + gb, &Bh[lr * 64]);
        GLL16(lo + gb, &Bl[lr * 64]);
    }
    __syncthreads();

    // ---- A fragments for this wave's 2 row-tiles ----
    int fr = l & 15;
    int s0 = l >> 4;                 // k-slot 0..3
    int r7 = l & 7;
    short8v aH[2][2], aL[2][2];
#pragma unroll
    for (int rt = 0; rt < 2; ++rt) {
        int base = (w * 32 + rt * 16 + fr) * 64;
        aH[rt][0] = *(const short8v*)&Ah[base + ((s0 ^ r7) << 3)];
        aH[rt][1] = *(const short8v*)&Ah[base + (((s0 + 4) ^ r7) << 3)];
        aL[rt][0] = *(const short8v*)&Al[base + ((s0 ^ r7) << 3)];
        aL[rt][1] = *(const short8v*)&Al[base + (((s0 + 4) ^ r7) << 3)];
    }

    f32x4 acc[2][8];
#pragma unroll
    for (int rt = 0; rt < 2; ++rt)
#pragma unroll
        for (int js = 0; js < 8; ++js) acc[rt][js] = (f32x4){0.f, 0.f, 0.f, 0.f};

#pragma unroll
    for (int js = 0; js < 8; ++js) {
        int bbase = (js * 16 + fr) * 64;
        short8v bH0 = *(const short8v*)&Bh[bbase + ((s0 ^ r7) << 3)];
        short8v bH1 = *(const short8v*)&Bh[bbase + (((s0 + 4) ^ r7) << 3)];
        short8v bL0 = *(const short8v*)&Bl[bbase + ((s0 ^ r7) << 3)];
        short8v bL1 = *(const short8v*)&Bl[bbase + (((s0 + 4) ^ r7) << 3)];
#pragma unroll
        for (int rt = 0; rt < 2; ++rt) {
            f32x4 a = acc[rt][js];
            a = __builtin_amdgcn_mfma_f32_16x16x32_bf16(aH[rt][0], bH0, a, 0, 0, 0);
            a = __builtin_amdgcn_mfma_f32_16x16x32_bf16(aH[rt][1], bH1, a, 0, 0, 0);
            a = __builtin_amdgcn_mfma_f32_16x16x32_bf16(aH[rt][0], bL0, a, 0, 0, 0);
            a = __builtin_amdgcn_mfma_f32_16x16x32_bf16(aH[rt][1], bL1, a, 0, 0, 0);
            a = __builtin_amdgcn_mfma_f32_16x16x32_bf16(aL[rt][0], bH0, a, 0, 0, 0);
            a = __builtin_amdgcn_mfma_f32_16x16x32_bf16(aL[rt][1], bH1, a, 0, 0, 0);
            acc[rt][js] = a;
        }
    }

    // ---- pack to bitmask. C/D layout: col=lane&15, row=(lane>>4)*4+reg ----
    int shift = ((l & 15) >> 2) * 16;
    int r = l & 3;
#pragma unroll
    for (int rt = 0; rt < 2; ++rt) {
#pragma unroll
        for (int ws_ = 0; ws_ < 2; ++ws_) {
            unsigned long long w64 = 0;
#pragma unroll
            for (int js2 = 0; js2 < 4; ++js2) {
                f32x4 a = acc[rt][ws_ * 4 + js2];
                unsigned long long c0 = __ballot(a[0] > 0.5f);
                unsigned long long c1 = __ballot(a[1] > 0.5f);
                unsigned long long c2 = __ballot(a[2] > 0.5f);
                unsigned long long c3 = __ballot(a[3] > 0.5f);
                unsigned long long sel = r == 0 ? c0 : r == 1 ? c1 : r == 2 ? c2 : c3;
                w64 |= ((sel >> shift) & 0xFFFFULL) << (js2 * 16);
            }
            if (l < 16)
                mask[(size_t)(i0 + w * 32 + rt * 16 + l) * 64 + blockIdx.x * 2 + ws_] = w64;
        }
    }
}

// ---------------------------------------------------------------------------
// K3: GAT-1 aggregation (+bias+ReLU) + mm2 + scores2. 4 rows/block, wave/row.
// ---------------------------------------------------------------------------
__global__ __launch_bounds__(256) void agg1_fused_kernel(
        const float* __restrict__ h1, const float* __restrict__ ssrc,
        const float* __restrict__ sdst, const unsigned long long* __restrict__ mask,
        const float* __restrict__ b1, const float* __restrict__ W2,
        const float* __restrict__ a2s, const float* __restrict__ a2d,
        float* __restrict__ h2out, float* __restrict__ s2s, float* __restrict__ s2d) {
    int row = blockIdx.x * 4 + (threadIdx.x >> 6);
    int i = row & (N_NODES - 1);
    int bN = row - i;
    int t = threadIdx.x & 63;
    int hh = t >> 4;

    float sd = sdst[(size_t)row * 4 + hh];
    unsigned long long myword = mask[(size_t)i * 64 + t];

    float m = -1e30f, denom = 0.f, acc = 0.f;
    unsigned long long nz = __ballot(myword != 0ULL);
    while (nz) {
        int lw = __ffsll(nz) - 1;
        nz &= nz - 1;
        unsigned long long wbits = __shfl(myword, lw);
        while (wbits) {
            int bpos = __ffsll(wbits) - 1;
            wbits &= wbits - 1;
            int j = (lw << 6) + bpos;
            float e = sd + ssrc[(size_t)(bN + j) * 4 + hh];
            e = e > 0.f ? e : 0.2f * e;
            float mn = fmaxf(m, e);
            float cf = __expf(m - mn);
            float wg = __expf(e - mn);
            float hv = h1[(size_t)(bN + j) * 64 + t];
            denom = denom * cf + wg;
            acc = acc * cf + wg * hv;
            m = mn;
        }
    }
    float o = fmaxf(acc / denom + b1[t], 0.f);   // out1 row, lane t = feature t

    // mm2: h2[t'] = sum_k o_k * W2[k*32+t']  (lanes 32..63 duplicate 0..31)
    int l2 = t & 31;
    float acc2 = 0.f;
#pragma unroll
    for (int k = 0; k < 64; ++k) acc2 += rl(o, k) * W2[k * 32 + l2];

    float ps = acc2 * a2s[l2], pd = acc2 * a2d[l2];
#pragma unroll
    for (int mm = 4; mm >= 1; mm >>= 1) {
        ps += __shfl_xor(ps, mm);
        pd += __shfl_xor(pd, mm);
    }
    if (t < 32) {
        h2out[(size_t)row * 32 + t] = acc2;
        if ((t & 7) == 0) {
            s2s[(size_t)row * 4 + (t >> 3)] = ps;
            s2d[(size_t)row * 4 + (t >> 3)] = pd;
        }
    }
}

// ---------------------------------------------------------------------------
// K4: GAT-2 aggregation -> d_out. 4 rows/block, wave/row.
// ---------------------------------------------------------------------------
__global__ __launch_bounds__(256) void agg2_kernel(
        const float* __restrict__ hfeat, const float* __restrict__ ssrc,
        const float* __restrict__ sdst, const unsigned long long* __restrict__ mask,
        const float* __restrict__ bias, float* __restrict__ out) {
    int row = blockIdx.x * 4 + (threadIdx.x >> 6);
    int i = row & (N_NODES - 1);
    int bN = row - i;
    int t = threadIdx.x & 63;
    int tt = t & 31;
    int hh = tt >> 3;

    float sd = sdst[(size_t)row * 4 + hh];
    unsigned long long myword = mask[(size_t)i * 64 + t];

    float m = -1e30f, denom = 0.f, acc = 0.f;
    unsigned long long nz = __ballot(myword != 0ULL);
    while (nz) {
        int lw = __ffsll(nz) - 1;
        nz &= nz - 1;
        unsigned long long wbits = __shfl(myword, lw);
        while (wbits) {
            int bpos = __ffsll(wbits) - 1;
            wbits &= wbits - 1;
            int j = (lw << 6) + bpos;
            float e = sd + ssrc[(size_t)(bN + j) * 4 + hh];
            e = e > 0.f ? e : 0.2f * e;
            float mn = fmaxf(m, e);
            float cf = __expf(m - mn);
            float wg = __expf(e - mn);
            float hv = hfeat[(size_t)(bN + j) * 32 + tt];
            denom = denom * cf + wg;
            acc = acc * cf + wg * hv;
            m = mn;
        }
    }
    float o = acc / denom + bias[tt];
    if (t < 32) out[(size_t)row * 32 + tt] = o;
}

// ---------------------------------------------------------------------------
extern "C" void kernel_launch(void* const* d_in, const int* in_sizes, int n_in,
                              void* d_out, int out_size, void* d_ws, size_t ws_size,
                              hipStream_t stream) {
    const float* x   = (const float*)d_in[0];
    const float* emb = (const float*)d_in[1];
    const float* Wp  = (const float*)d_in[2];
    const float* bp  = (const float*)d_in[3];
    const float* W1  = (const float*)d_in[4];
    const float* a1s = (const float*)d_in[5];
    const float* a1d = (const float*)d_in[6];
    const float* b1  = (const float*)d_in[7];
    const float* W2  = (const float*)d_in[8];
    const float* a2s = (const float*)d_in[9];
    const float* a2d = (const float*)d_in[10];
    const float* b2  = (const float*)d_in[11];

    const int ROWS = BATCH * N_NODES;  // 8192

    char* w = (char*)d_ws;
    unsigned short* ne_hi = (unsigned short*)w;  w += (size_t)N_NODES * 64 * 2;
    unsigned short* ne_lo = (unsigned short*)w;  w += (size_t)N_NODES * 64 * 2;
    unsigned long long* mask = (unsigned long long*)w; w += (size_t)N_NODES * 64 * 8;
    float* h1  = (float*)w;                      w += (size_t)ROWS * 64 * 4;
    float* s1s = (float*)w;                      w += (size_t)ROWS * 4 * 4;
    float* s1d = (float*)w;                      w += (size_t)ROWS * 4 * 4;
    float* h2  = (float*)w;                      w += (size_t)ROWS * 32 * 4;
    float* s2s = (float*)w;                      w += (size_t)ROWS * 4 * 4;
    float* s2d = (float*)w;                      w += (size_t)ROWS * 4 * 4;

    k1_kernel<<<dim3(512), dim3(256), 0, stream>>>(
        emb, ne_hi, ne_lo, x, Wp, bp, W1, a1s, a1d, h1, s1s, s1d);
    adj_mfma_kernel<<<dim3(32, 32), dim3(256), 0, stream>>>(ne_hi, ne_lo, mask);
    agg1_fused_kernel<<<dim3(ROWS / 4), dim3(256), 0, stream>>>(
        h1, s1s, s1d, mask, b1, W2, a2s, a2d, h2, s2s, s2d);
    agg2_kernel<<<dim3(ROWS / 4), dim3(256), 0, stream>>>(
        h2, s2s, s2d, mask, b2, (float*)d_out);
}